// Round 2
// baseline (927.328 us; speedup 1.0000x reference)
//
#include <hip/hip_runtime.h>
#include <hip/hip_bf16.h>
#include <stdint.h>

using bf16x8 = __attribute__((ext_vector_type(8))) short;
using f32x4  = __attribute__((ext_vector_type(4))) float;

__device__ __forceinline__ void gload_lds16(const void* g, void* l) {
  __builtin_amdgcn_global_load_lds(
      (const __attribute__((address_space(1))) void*)g,
      (__attribute__((address_space(3))) void*)l,
      16, 0, 0);
}

__device__ __forceinline__ short f2bf(float f) {
  union { float f; uint32_t u; } c; c.f = f;
  uint32_t u = c.u;
  uint32_t r = (u + 0x7fffu + ((u >> 16) & 1u)) >> 16;  // RNE
  return (short)(r & 0xffffu);
}

// ---- L2-normalize rows of 1024 f32 -> bf16. One 256-thread block per row.
__global__ __launch_bounds__(256) void norm_rows(
    const float* __restrict__ F, const float* __restrict__ P,
    short* __restrict__ Fb, short* __restrict__ Pb, int nF) {
  int row = blockIdx.x;
  const float* src; short* dst;
  if (row < nF) {
    src = F + (size_t)row * 1024; dst = Fb + (size_t)row * 1024;
  } else {
    int r = row - nF;
    src = P + (size_t)r * 1024; dst = Pb + (size_t)r * 1024;
  }
  int tid = threadIdx.x;
  float4 v = ((const float4*)src)[tid];   // 256 thr x 16B = 1024 floats
  float ss = v.x * v.x + v.y * v.y + v.z * v.z + v.w * v.w;
  #pragma unroll
  for (int off = 32; off >= 1; off >>= 1) ss += __shfl_xor(ss, off);
  __shared__ float wsum[4];
  if ((tid & 63) == 0) wsum[tid >> 6] = ss;
  __syncthreads();
  float tot = wsum[0] + wsum[1] + wsum[2] + wsum[3];
  float inv = 1.0f / fmaxf(sqrtf(tot), 1e-12f);
  short4 o;
  o.x = f2bf(v.x * inv); o.y = f2bf(v.y * inv);
  o.z = f2bf(v.z * inv); o.w = f2bf(v.w * inv);
  ((short4*)dst)[tid] = o;
}

// ---- bf16 NT GEMM (A[M][K] . B[C][K]^T) with IsoMax epilogue.
// m97 structure: 128x128 tile, BK=32, 4 waves, 16x16x32 MFMA, 4x4 frags/wave,
// global_load_lds width=16 staging, 2-barrier K-loop.
#define BM 128
#define BN 128
#define BK 32

__global__ __launch_bounds__(256) void gemm_epi(
    const short* __restrict__ A,   // [M][K] bf16 bits
    const short* __restrict__ B,   // [Cc][K] bf16 bits
    const float* __restrict__ scale,
    float* __restrict__ Out, int M, int Cc, int K) {
  __shared__ __align__(16) short As[BM * BK];
  __shared__ __align__(16) short Bs[BN * BK];

  const int tid  = threadIdx.x;
  const int wave = tid >> 6;
  const int lane = tid & 63;

  // XCD-aware bijective swizzle (grid 8192, %8==0)
  const int nwg = gridDim.x;
  const int cpx = nwg >> 3;
  const int bid = blockIdx.x;
  const int swz = (bid & 7) * cpx + (bid >> 3);
  const int ntn = Cc / BN;
  const int tm = swz / ntn;
  const int tn = swz % ntn;

  const short* Abase = A + (size_t)tm * BM * K;
  const short* Bbase = B + (size_t)tn * BN * K;

  // staging: wave w covers tile rows [w*32, w*32+32); 2 issues of 16 rows.
  // lane l -> row w*32 + (l>>2) (+16 for issue 1), bytes (l&3)*16 within row.
  const int srow = wave * 32 + (lane >> 2);
  const int scol = (lane & 3) * 8;           // element offset (8 bf16 = 16B)

  // compute: wave quadrant (wr,wc) of 64x64; 4x4 fragments of 16x16.
  const int wr = wave >> 1, wc = wave & 1;
  const int fr = lane & 15;                  // A row / B col within fragment
  const int fk = (lane >> 4) * 8;            // K offset within BK

  f32x4 acc[4][4];
  #pragma unroll
  for (int i = 0; i < 4; ++i)
    #pragma unroll
    for (int j = 0; j < 4; ++j)
      acc[i][j] = (f32x4){0.f, 0.f, 0.f, 0.f};

  for (int k0 = 0; k0 < K; k0 += BK) {
    const short* ag = Abase + (size_t)srow * K + k0 + scol;
    const short* bg = Bbase + (size_t)srow * K + k0 + scol;
    gload_lds16(ag,          &As[(wave * 32) * BK]);
    gload_lds16(ag + 16 * K, &As[(wave * 32 + 16) * BK]);
    gload_lds16(bg,          &Bs[(wave * 32) * BK]);
    gload_lds16(bg + 16 * K, &Bs[(wave * 32 + 16) * BK]);
    __syncthreads();   // compiler drains vmcnt before s_barrier

    bf16x8 af[4], bfr[4];
    #pragma unroll
    for (int mi = 0; mi < 4; ++mi)
      af[mi] = *(const bf16x8*)&As[(wr * 64 + mi * 16 + fr) * BK + fk];
    #pragma unroll
    for (int ni = 0; ni < 4; ++ni)
      bfr[ni] = *(const bf16x8*)&Bs[(wc * 64 + ni * 16 + fr) * BK + fk];
    #pragma unroll
    for (int mi = 0; mi < 4; ++mi)
      #pragma unroll
      for (int ni = 0; ni < 4; ++ni)
        acc[mi][ni] = __builtin_amdgcn_mfma_f32_16x16x32_bf16(
            af[mi], bfr[ni], acc[mi][ni], 0, 0, 0);
    __syncthreads();
  }

  // epilogue: out = -|s| * sqrt(max(2 - 2*dot, 1e-12))
  const float s = fabsf(scale[0]);
  const int col0  = tn * BN + wc * 64 + (lane & 15);
  const int row00 = tm * BM + wr * 64 + (lane >> 4) * 4;
  #pragma unroll
  for (int mi = 0; mi < 4; ++mi) {
    #pragma unroll
    for (int ni = 0; ni < 4; ++ni) {
      f32x4 a = acc[mi][ni];
      const int col = col0 + ni * 16;
      #pragma unroll
      for (int r = 0; r < 4; ++r) {
        float d  = a[r];
        float sq = fmaxf(2.0f - 2.0f * d, 1e-12f);
        Out[(size_t)(row00 + mi * 16 + r) * Cc + col] = -s * sqrtf(sq);
      }
    }
  }
}

extern "C" void kernel_launch(void* const* d_in, const int* in_sizes, int n_in,
                              void* d_out, int out_size, void* d_ws, size_t ws_size,
                              hipStream_t stream) {
  const float* F = (const float*)d_in[0];   // features  [N][1024] f32
  const float* P = (const float*)d_in[1];   // prototypes[C][1024] f32
  const float* S = (const float*)d_in[2];   // distance_scale [1]
  float* Out = (float*)d_out;               // [N][C] f32

  const int D = 1024;
  const int N = in_sizes[0] / D;            // 16384
  const int C = in_sizes[1] / D;            // 8192

  short* Fb = (short*)d_ws;                 // bf16 [N][D]  (32 MiB)
  short* Pb = Fb + (size_t)N * D;           // bf16 [C][D]  (16 MiB)

  norm_rows<<<N + C, 256, 0, stream>>>(F, P, Fb, Pb, N);

  dim3 grid((N / BM) * (C / BN));           // 128 * 64 = 8192 tiles
  gemm_epi<<<grid, 256, 0, stream>>>(Fb, Pb, S, Out, N, C, D);
}

// Round 3
// 845.418 us; speedup vs baseline: 1.0969x; 1.0969x over previous
//
#include <hip/hip_runtime.h>
#include <hip/hip_bf16.h>
#include <stdint.h>

using bf16x8 = __attribute__((ext_vector_type(8))) short;
using f32x4  = __attribute__((ext_vector_type(4))) float;

#define SBAR()   __builtin_amdgcn_s_barrier()
#define SCHED0() __builtin_amdgcn_sched_barrier(0)
#define LGKM0()  asm volatile("s_waitcnt lgkmcnt(0)" ::: "memory")
#define VM0()    asm volatile("s_waitcnt vmcnt(0)" ::: "memory")

__device__ __forceinline__ void gload_lds16(const void* g, void* l) {
  __builtin_amdgcn_global_load_lds(
      (const __attribute__((address_space(1))) void*)g,
      (__attribute__((address_space(3))) void*)l,
      16, 0, 0);
}

__device__ __forceinline__ short f2bf(float f) {
  union { float f; uint32_t u; } c; c.f = f;
  uint32_t u = c.u;
  uint32_t r = (u + 0x7fffu + ((u >> 16) & 1u)) >> 16;  // RNE
  return (short)(r & 0xffffu);
}

// ---- L2-normalize rows of 1024 f32 -> bf16. One 256-thread block per row.
__global__ __launch_bounds__(256) void norm_rows(
    const float* __restrict__ F, const float* __restrict__ P,
    short* __restrict__ Fb, short* __restrict__ Pb, int nF) {
  int row = blockIdx.x;
  const float* src; short* dst;
  if (row < nF) {
    src = F + (size_t)row * 1024; dst = Fb + (size_t)row * 1024;
  } else {
    int r = row - nF;
    src = P + (size_t)r * 1024; dst = Pb + (size_t)r * 1024;
  }
  int tid = threadIdx.x;
  float4 v = ((const float4*)src)[tid];
  float ss = v.x * v.x + v.y * v.y + v.z * v.z + v.w * v.w;
  #pragma unroll
  for (int off = 32; off >= 1; off >>= 1) ss += __shfl_xor(ss, off);
  __shared__ float wsum[4];
  if ((tid & 63) == 0) wsum[tid >> 6] = ss;
  __syncthreads();
  float tot = wsum[0] + wsum[1] + wsum[2] + wsum[3];
  float inv = 1.0f / fmaxf(sqrtf(tot), 1e-12f);
  short4 o;
  o.x = f2bf(v.x * inv); o.y = f2bf(v.y * inv);
  o.z = f2bf(v.z * inv); o.w = f2bf(v.w * inv);
  ((short4*)dst)[tid] = o;
}

// ---- 256x256 8-phase bf16 NT GEMM with IsoMax epilogue.
// 8 waves (2M x 4N), per-wave 128x64 out. BK=64, double-buffered LDS 128 KiB.
// st_16x32 subtiled+XOR-swizzled LDS; linear gload_lds dest + inverse-swizzled
// global source; raw s_barrier phases; boundary vmcnt(0) only.
#define BM 256
#define BN 256
#define BK 64

__global__ __launch_bounds__(512, 2) void gemm_epi(
    const short* __restrict__ A,   // [M][K] bf16 bits (normalized features)
    const short* __restrict__ B,   // [Cc][K] bf16 bits (normalized prototypes)
    const float* __restrict__ scale,
    float* __restrict__ Out, int M, int Cc, int K) {
  __shared__ __align__(16) char smem[2 * 65536];   // [buf][A 32K | B 32K]

  const int tid  = threadIdx.x;
  const int wave = tid >> 6;
  const int lane = tid & 63;
  const int wm = wave >> 2;          // 0..1 : M half (128 rows)
  const int wn = wave & 3;           // 0..3 : N quarter (64 cols)
  const int hb = wn >> 1;            // B half for this wave
  const int rbB = (wn & 1) * 4;      // B subtile row-block base within half

  // XCD-aware bijective swizzle (grid 2048, %8==0)
  const int nwg = gridDim.x;
  const int cpx = nwg >> 3;
  const int swz = (blockIdx.x & 7) * cpx + (blockIdx.x >> 3);
  const int ntn = Cc / BN;
  const int tm = swz / ntn, tn = swz % ntn;

  const size_t Kb = (size_t)K * 2;   // global row stride (bytes)
  const char* Ag = (const char*)A + (size_t)tm * BM * Kb;
  const char* Bg = (const char*)B + (size_t)tn * BN * Kb;

  // Staging inverse map: LDS slot s (linear, within 16KB half-tile) ->
  // (row, colbyte) of the [128][64] bf16 half-tile in st_16x32 swizzled
  // subtile layout (16 subtiles of 1024B; byte ^= ((byte>>9)&1)<<5).
  int r0, c0, r1, c1;
  { int s = tid * 16;        int st = s >> 10, w = s & 1023;
    w ^= ((w >> 9) & 1) << 5; r0 = ((st >> 1) << 4) + (w >> 6); c0 = ((st & 1) << 6) + (w & 63); }
  { int s = 8192 + tid * 16; int st = s >> 10, w = s & 1023;
    w ^= ((w >> 9) & 1) << 5; r1 = ((st >> 1) << 4) + (w >> 6); c1 = ((st & 1) << 6) + (w & 63); }

  // Fragment read offset within a 1024B subtile (same swizzle).
  const int fr  = lane & 15;
  const int fk2 = ((lane >> 4) * 8) * 2;                  // {0,16,32,48} bytes
  const int fragoff = fr * 64 + (fk2 ^ ((fr & 8) ? 32 : 0));

  const char* smA = smem + wm * 16384;                    // + buf*65536 + (mi*2+ks)*1024
  const char* smB = smem + 32768 + hb * 16384;            // + buf*65536 + ((rbB+ni)*2+ks)*1024

  f32x4 acc[8][4];
  #pragma unroll
  for (int i = 0; i < 8; ++i)
    #pragma unroll
    for (int j = 0; j < 4; ++j) acc[i][j] = (f32x4){0.f, 0.f, 0.f, 0.f};

  const int nt = K / BK;

  #define STAGE(t, buf) do {                                                   \
    const size_t kb = (size_t)(t) * (BK * 2);                                  \
    char* db = smem + (buf) * 65536 + wave * 1024;                             \
    gload_lds16(Ag + (size_t)(      r0) * Kb + kb + c0, db);                   \
    gload_lds16(Ag + (size_t)(      r1) * Kb + kb + c1, db + 8192);            \
    gload_lds16(Ag + (size_t)(128 + r0) * Kb + kb + c0, db + 16384);           \
    gload_lds16(Ag + (size_t)(128 + r1) * Kb + kb + c1, db + 16384 + 8192);    \
    gload_lds16(Bg + (size_t)(      r0) * Kb + kb + c0, db + 32768);           \
    gload_lds16(Bg + (size_t)(      r1) * Kb + kb + c1, db + 32768 + 8192);    \
    gload_lds16(Bg + (size_t)(128 + r0) * Kb + kb + c0, db + 49152);           \
    gload_lds16(Bg + (size_t)(128 + r1) * Kb + kb + c1, db + 49152 + 8192);    \
  } while (0)

  #define LDA(buf, mi, ks) (*(const bf16x8*)(smA + (buf) * 65536 + ((mi) * 2 + (ks)) * 1024 + fragoff))
  #define LDB(buf, ni, ks) (*(const bf16x8*)(smB + (buf) * 65536 + ((rbB + (ni)) * 2 + (ks)) * 1024 + fragoff))

  STAGE(0, 0);
  VM0(); SCHED0(); SBAR(); SCHED0();

  for (int t = 0; t < nt; ++t) {
    const int cur = t & 1, nxt = cur ^ 1;
    if (t + 1 < nt) STAGE(t + 1, nxt);   // front-loaded: 4 phases of cover

    // ---- phase 0: quadrant (mi 0-3, ni 0-1)
    bf16x8 a03[4][2], b01[2][2];
    #pragma unroll
    for (int mi = 0; mi < 4; ++mi) { a03[mi][0] = LDA(cur, mi, 0); a03[mi][1] = LDA(cur, mi, 1); }
    #pragma unroll
    for (int ni = 0; ni < 2; ++ni) { b01[ni][0] = LDB(cur, ni, 0); b01[ni][1] = LDB(cur, ni, 1); }
    SBAR(); LGKM0(); SCHED0();
    __builtin_amdgcn_s_setprio(1);
    #pragma unroll
    for (int mi = 0; mi < 4; ++mi)
      #pragma unroll
      for (int ni = 0; ni < 2; ++ni) {
        acc[mi][ni] = __builtin_amdgcn_mfma_f32_16x16x32_bf16(a03[mi][0], b01[ni][0], acc[mi][ni], 0, 0, 0);
        acc[mi][ni] = __builtin_amdgcn_mfma_f32_16x16x32_bf16(a03[mi][1], b01[ni][1], acc[mi][ni], 0, 0, 0);
      }
    __builtin_amdgcn_s_setprio(0);
    SBAR(); SCHED0();

    // ---- phase 1: quadrant (mi 0-3, ni 2-3)  [A reused]
    bf16x8 b23[2][2];
    #pragma unroll
    for (int ni = 0; ni < 2; ++ni) { b23[ni][0] = LDB(cur, 2 + ni, 0); b23[ni][1] = LDB(cur, 2 + ni, 1); }
    SBAR(); LGKM0(); SCHED0();
    __builtin_amdgcn_s_setprio(1);
    #pragma unroll
    for (int mi = 0; mi < 4; ++mi)
      #pragma unroll
      for (int ni = 0; ni < 2; ++ni) {
        acc[mi][2 + ni] = __builtin_amdgcn_mfma_f32_16x16x32_bf16(a03[mi][0], b23[ni][0], acc[mi][2 + ni], 0, 0, 0);
        acc[mi][2 + ni] = __builtin_amdgcn_mfma_f32_16x16x32_bf16(a03[mi][1], b23[ni][1], acc[mi][2 + ni], 0, 0, 0);
      }
    __builtin_amdgcn_s_setprio(0);
    SBAR(); SCHED0();

    // ---- phase 2: quadrant (mi 4-7, ni 2-3)  [B reused]
    bf16x8 a47[4][2];
    #pragma unroll
    for (int mi = 0; mi < 4; ++mi) { a47[mi][0] = LDA(cur, 4 + mi, 0); a47[mi][1] = LDA(cur, 4 + mi, 1); }
    SBAR(); LGKM0(); SCHED0();
    __builtin_amdgcn_s_setprio(1);
    #pragma unroll
    for (int mi = 0; mi < 4; ++mi)
      #pragma unroll
      for (int ni = 0; ni < 2; ++ni) {
        acc[4 + mi][2 + ni] = __builtin_amdgcn_mfma_f32_16x16x32_bf16(a47[mi][0], b23[ni][0], acc[4 + mi][2 + ni], 0, 0, 0);
        acc[4 + mi][2 + ni] = __builtin_amdgcn_mfma_f32_16x16x32_bf16(a47[mi][1], b23[ni][1], acc[4 + mi][2 + ni], 0, 0, 0);
      }
    __builtin_amdgcn_s_setprio(0);
    SBAR(); SCHED0();

    // ---- phase 3: quadrant (mi 4-7, ni 0-1)  [B re-read]
    bf16x8 b01b[2][2];
    #pragma unroll
    for (int ni = 0; ni < 2; ++ni) { b01b[ni][0] = LDB(cur, ni, 0); b01b[ni][1] = LDB(cur, ni, 1); }
    SBAR(); LGKM0(); SCHED0();
    __builtin_amdgcn_s_setprio(1);
    #pragma unroll
    for (int mi = 0; mi < 4; ++mi)
      #pragma unroll
      for (int ni = 0; ni < 2; ++ni) {
        acc[4 + mi][ni] = __builtin_amdgcn_mfma_f32_16x16x32_bf16(a47[mi][0], b01b[ni][0], acc[4 + mi][ni], 0, 0, 0);
        acc[4 + mi][ni] = __builtin_amdgcn_mfma_f32_16x16x32_bf16(a47[mi][1], b01b[ni][1], acc[4 + mi][ni], 0, 0, 0);
      }
    __builtin_amdgcn_s_setprio(0);
    VM0(); SCHED0();   // boundary: next tile's staged data must be in LDS
    SBAR(); SCHED0();
  }

  // epilogue: out = -|s| * sqrt(max(2 - 2*dot, 1e-12)), nontemporal stores
  const float sc = fabsf(scale[0]);
  const int orow0 = tm * BM + wm * 128 + (lane >> 4) * 4;
  const int ocol0 = tn * BN + wn * 64 + fr;
  #pragma unroll
  for (int mi = 0; mi < 8; ++mi) {
    #pragma unroll
    for (int ni = 0; ni < 4; ++ni) {
      const int col = ocol0 + ni * 16;
      #pragma unroll
      for (int r = 0; r < 4; ++r) {
        float d  = acc[mi][ni][r];
        float sq = fmaxf(2.0f - 2.0f * d, 1e-12f);
        __builtin_nontemporal_store(-sc * sqrtf(sq),
            &Out[(size_t)(orow0 + mi * 16 + r) * Cc + col]);
      }
    }
  }
  #undef STAGE
  #undef LDA
  #undef LDB
}

extern "C" void kernel_launch(void* const* d_in, const int* in_sizes, int n_in,
                              void* d_out, int out_size, void* d_ws, size_t ws_size,
                              hipStream_t stream) {
  const float* F = (const float*)d_in[0];
  const float* P = (const float*)d_in[1];
  const float* S = (const float*)d_in[2];
  float* Out = (float*)d_out;

  const int D = 1024;
  const int N = in_sizes[0] / D;            // 16384
  const int C = in_sizes[1] / D;            // 8192

  short* Fb = (short*)d_ws;                 // bf16 [N][D]
  short* Pb = Fb + (size_t)N * D;           // bf16 [C][D]

  norm_rows<<<N + C, 256, 0, stream>>>(F, P, Fb, Pb, N);

  dim3 grid((N / BM) * (C / BN));           // 64 * 32 = 2048 tiles
  gemm_epi<<<grid, 512, 0, stream>>>(Fb, Pb, S, Out, N, C, D);
}

// Round 4
// 820.844 us; speedup vs baseline: 1.1297x; 1.0299x over previous
//
#include <hip/hip_runtime.h>
#include <hip/hip_bf16.h>
#include <stdint.h>

using bf16x8 = __attribute__((ext_vector_type(8))) short;
using f32x4  = __attribute__((ext_vector_type(4))) float;

#define SBAR()   __builtin_amdgcn_s_barrier()
#define SCHED0() __builtin_amdgcn_sched_barrier(0)
#define LGKM0()  asm volatile("s_waitcnt lgkmcnt(0)" ::: "memory")
#define VMW(n)   asm volatile("s_waitcnt vmcnt(" #n ")" ::: "memory")

__device__ __forceinline__ void gload_lds16(const void* g, void* l) {
  __builtin_amdgcn_global_load_lds(
      (const __attribute__((address_space(1))) void*)g,
      (__attribute__((address_space(3))) void*)l,
      16, 0, 0);
}

__device__ __forceinline__ short f2bf(float f) {
  union { float f; uint32_t u; } c; c.f = f;
  uint32_t u = c.u;
  uint32_t r = (u + 0x7fffu + ((u >> 16) & 1u)) >> 16;  // RNE
  return (short)(r & 0xffffu);
}

// ---- L2-normalize rows of 1024 f32 -> bf16. One 256-thread block per row.
__global__ __launch_bounds__(256) void norm_rows(
    const float* __restrict__ F, const float* __restrict__ P,
    short* __restrict__ Fb, short* __restrict__ Pb, int nF) {
  int row = blockIdx.x;
  const float* src; short* dst;
  if (row < nF) {
    src = F + (size_t)row * 1024; dst = Fb + (size_t)row * 1024;
  } else {
    int r = row - nF;
    src = P + (size_t)r * 1024; dst = Pb + (size_t)r * 1024;
  }
  int tid = threadIdx.x;
  float4 v = ((const float4*)src)[tid];
  float ss = v.x * v.x + v.y * v.y + v.z * v.z + v.w * v.w;
  #pragma unroll
  for (int off = 32; off >= 1; off >>= 1) ss += __shfl_xor(ss, off);
  __shared__ float wsum[4];
  if ((tid & 63) == 0) wsum[tid >> 6] = ss;
  __syncthreads();
  float tot = wsum[0] + wsum[1] + wsum[2] + wsum[3];
  float inv = 1.0f / fmaxf(sqrtf(tot), 1e-12f);
  short4 o;
  o.x = f2bf(v.x * inv); o.y = f2bf(v.y * inv);
  o.z = f2bf(v.z * inv); o.w = f2bf(v.w * inv);
  ((short4*)dst)[tid] = o;
}

// ---- 256x256 bf16 NT GEMM, 8-phase counted-vmcnt schedule (T2+T3+T4+T5).
// 8 waves (2M x 4N), per-wave 128x64 out. 2 K-tiles (BK=64 each) per iter,
// double-buffered 128 KiB LDS, st_16x32 swizzle, per-phase 2-load staging in
// read-deadline order (Blo,Bhi,Aev,Aod) -> steady-state waits vmcnt(2)/(4).
#define BM 256
#define BN 256
#define BK 64

__global__ __launch_bounds__(512, 2) void gemm_epi(
    const short* __restrict__ A,   // [M][K] bf16 bits (normalized features)
    const short* __restrict__ B,   // [Cc][K] bf16 bits (normalized prototypes)
    const float* __restrict__ scale,
    float* __restrict__ Out, int M, int Cc, int K) {
  __shared__ __align__(16) char smem[2 * 65536];   // [buf][A 32K | B 32K]

  const int tid  = threadIdx.x;
  const int wave = tid >> 6;
  const int lane = tid & 63;
  const int wm = wave >> 2;          // 0..1 : M half (128 rows)
  const int wn = wave & 3;           // 0..3 : N quarter (64 cols)
  const int hb = wn >> 1;            // B half for this wave
  const int rbB = (wn & 1) * 4;      // B subtile row-block base within half

  // XCD-aware bijective swizzle (grid 2048, %8==0)
  const int nwg = gridDim.x;
  const int cpx = nwg >> 3;
  const int swz = (blockIdx.x & 7) * cpx + (blockIdx.x >> 3);
  const int ntn = Cc / BN;
  const int tm = swz / ntn, tn = swz % ntn;

  const size_t Kb = (size_t)K * 2;   // global row stride (bytes)
  const char* Ag = (const char*)A + (size_t)tm * BM * Kb;
  const char* Bg = (const char*)B + (size_t)tn * BN * Kb;

  // Staging inverse map: LDS slot (linear) -> (row,colbyte) of the [128][64]
  // bf16 half-tile in st_16x32 swizzled subtile layout.
  int r0, c0, r1, c1;
  { int s = tid * 16;        int st = s >> 10, w = s & 1023;
    w ^= ((w >> 9) & 1) << 5; r0 = ((st >> 1) << 4) + (w >> 6); c0 = ((st & 1) << 6) + (w & 63); }
  { int s = 8192 + tid * 16; int st = s >> 10, w = s & 1023;
    w ^= ((w >> 9) & 1) << 5; r1 = ((st >> 1) << 4) + (w >> 6); c1 = ((st & 1) << 6) + (w & 63); }

  // Fragment read offset within a 1024B subtile (same swizzle).
  const int fr  = lane & 15;
  const int fk2 = ((lane >> 4) * 8) * 2;                  // {0,16,32,48} bytes
  const int fragoff = fr * 64 + (fk2 ^ ((fr & 8) ? 32 : 0));

  const char* smA = smem + wm * 16384;
  const char* smB = smem + 32768 + hb * 16384;

  f32x4 acc[8][4];
  #pragma unroll
  for (int i = 0; i < 8; ++i)
    #pragma unroll
    for (int j = 0; j < 4; ++j) acc[i][j] = (f32x4){0.f, 0.f, 0.f, 0.f};

  // --- staging pairs (2 gload_lds each), read-deadline order ---
  // pair 1: B-low both subhalves | pair 2: B-high | pair 3: A mi0-3 of both
  // halves | pair 4: A mi4-7.  First 6 loads needed at ph0, last 2 at ph2.
  #define STG_BLO(t, buf) do { const size_t kb = (size_t)(t) * (BK * 2);       \
    char* db = smem + (buf) * 65536 + wave * 1024;                             \
    gload_lds16(Bg + (size_t)(      r0) * Kb + kb + c0, db + 32768);           \
    gload_lds16(Bg + (size_t)(      r1) * Kb + kb + c1, db + 40960); } while (0)
  #define STG_BHI(t, buf) do { const size_t kb = (size_t)(t) * (BK * 2);       \
    char* db = smem + (buf) * 65536 + wave * 1024;                             \
    gload_lds16(Bg + (size_t)(128 + r0) * Kb + kb + c0, db + 49152);           \
    gload_lds16(Bg + (size_t)(128 + r1) * Kb + kb + c1, db + 57344); } while (0)
  #define STG_AEV(t, buf) do { const size_t kb = (size_t)(t) * (BK * 2);       \
    char* db = smem + (buf) * 65536 + wave * 1024;                             \
    gload_lds16(Ag + (size_t)(      r0) * Kb + kb + c0, db);                   \
    gload_lds16(Ag + (size_t)(128 + r0) * Kb + kb + c0, db + 16384); } while (0)
  #define STG_AOD(t, buf) do { const size_t kb = (size_t)(t) * (BK * 2);       \
    char* db = smem + (buf) * 65536 + wave * 1024;                             \
    gload_lds16(Ag + (size_t)(      r1) * Kb + kb + c1, db + 8192);            \
    gload_lds16(Ag + (size_t)(128 + r1) * Kb + kb + c1, db + 24576); } while (0)

  #define LDA(buf, mi, ks) (*(const bf16x8*)(smA + (buf) * 65536 + ((mi) * 2 + (ks)) * 1024 + fragoff))
  #define LDB(buf, nj, ks) (*(const bf16x8*)(smB + (buf) * 65536 + ((rbB + (nj)) * 2 + (ks)) * 1024 + fragoff))

  #define RD_A(AR, buf, mbase)                                                 \
    _Pragma("unroll")                                                          \
    for (int mi = 0; mi < 4; ++mi) {                                           \
      AR[mi][0] = LDA(buf, (mbase) + mi, 0);                                   \
      AR[mi][1] = LDA(buf, (mbase) + mi, 1); }
  #define RD_B(BR, buf, nbase)                                                 \
    _Pragma("unroll")                                                          \
    for (int nj = 0; nj < 2; ++nj) {                                           \
      BR[nj][0] = LDB(buf, (nbase) + nj, 0);                                   \
      BR[nj][1] = LDB(buf, (nbase) + nj, 1); }
  #define MFMA_Q(mbase, nbase, AR, BR)                                         \
    _Pragma("unroll")                                                          \
    for (int mi = 0; mi < 4; ++mi)                                             \
      _Pragma("unroll")                                                        \
      for (int nj = 0; nj < 2; ++nj) {                                         \
        acc[(mbase)+mi][(nbase)+nj] = __builtin_amdgcn_mfma_f32_16x16x32_bf16( \
            AR[mi][0], BR[nj][0], acc[(mbase)+mi][(nbase)+nj], 0, 0, 0);       \
        acc[(mbase)+mi][(nbase)+nj] = __builtin_amdgcn_mfma_f32_16x16x32_bf16( \
            AR[mi][1], BR[nj][1], acc[(mbase)+mi][(nbase)+nj], 0, 0, 0); }

  const int ni = K / (2 * BK);   // iterations; 2 K-tiles each

  // Prologue: stage tile 0 -> buf0; wait first 6 (B all + A mi0-3).
  STG_BLO(0, 0); STG_BHI(0, 0); STG_AEV(0, 0); STG_AOD(0, 0); SCHED0();
  VMW(2); SCHED0(); SBAR(); SCHED0();

  for (int i = 0; i < ni; ++i) {
    const int t1 = 2 * i + 1;          // staged ph0-3 -> buf1, read ph4-7
    const int t2 = 2 * i + 2;          // staged ph4-7 -> buf0, read next iter
    const bool last = (i == ni - 1);

    bf16x8 a03[4][2], a47[4][2], bA[2][2], bB[2][2];

    // ph0: tile 2i quadrant (mi0-3, ni0-1)
    RD_A(a03, 0, 0); RD_B(bA, 0, 0);
    STG_BLO(t1, 1); SCHED0();
    SBAR(); LGKM0(); SCHED0();
    __builtin_amdgcn_s_setprio(1); MFMA_Q(0, 0, a03, bA) __builtin_amdgcn_s_setprio(0);
    SBAR(); SCHED0();

    // ph1: (mi0-3, ni2-3)  [A reused]
    RD_B(bB, 0, 2);
    STG_BHI(t1, 1); SCHED0();
    SBAR(); LGKM0(); SCHED0();
    __builtin_amdgcn_s_setprio(1); MFMA_Q(0, 2, a03, bB) __builtin_amdgcn_s_setprio(0);
    VMW(4); SCHED0();                  // protect ph2: tile 2i A mi4-7 landed
    SBAR(); SCHED0();

    // ph2: (mi4-7, ni2-3)  [B reused]
    RD_A(a47, 0, 4);
    STG_AEV(t1, 1); SCHED0();
    SBAR(); LGKM0(); SCHED0();
    __builtin_amdgcn_s_setprio(1); MFMA_Q(4, 2, a47, bB) __builtin_amdgcn_s_setprio(0);
    SBAR(); SCHED0();

    // ph3: (mi4-7, ni0-1)  [B re-read]
    RD_B(bA, 0, 0);
    STG_AOD(t1, 1); SCHED0();
    SBAR(); LGKM0(); SCHED0();
    __builtin_amdgcn_s_setprio(1); MFMA_Q(4, 0, a47, bA) __builtin_amdgcn_s_setprio(0);
    VMW(2); SCHED0();                  // protect ph4: tile t1 first-6 landed
    SBAR(); SCHED0();

    // ph4: tile t1 quadrant (mi0-3, ni0-1)
    RD_A(a03, 1, 0); RD_B(bA, 1, 0);
    if (!last) { STG_BLO(t2, 0); } SCHED0();
    SBAR(); LGKM0(); SCHED0();
    __builtin_amdgcn_s_setprio(1); MFMA_Q(0, 0, a03, bA) __builtin_amdgcn_s_setprio(0);
    SBAR(); SCHED0();

    // ph5: (mi0-3, ni2-3)
    RD_B(bB, 1, 2);
    if (!last) { STG_BHI(t2, 0); } SCHED0();
    SBAR(); LGKM0(); SCHED0();
    __builtin_amdgcn_s_setprio(1); MFMA_Q(0, 2, a03, bB) __builtin_amdgcn_s_setprio(0);
    if (!last) { VMW(4); } else { VMW(0); }   // protect ph6: t1 A mi4-7 landed
    SCHED0();
    SBAR(); SCHED0();

    // ph6: (mi4-7, ni2-3)
    RD_A(a47, 1, 4);
    if (!last) { STG_AEV(t2, 0); } SCHED0();
    SBAR(); LGKM0(); SCHED0();
    __builtin_amdgcn_s_setprio(1); MFMA_Q(4, 2, a47, bB) __builtin_amdgcn_s_setprio(0);
    SBAR(); SCHED0();

    // ph7: (mi4-7, ni0-1)
    RD_B(bA, 1, 0);
    if (!last) { STG_AOD(t2, 0); } SCHED0();
    SBAR(); LGKM0(); SCHED0();
    __builtin_amdgcn_s_setprio(1); MFMA_Q(4, 0, a47, bA) __builtin_amdgcn_s_setprio(0);
    VMW(2); SCHED0();                  // protect next ph0: t2 first-6 landed
    SBAR(); SCHED0();
  }

  // epilogue: out = -|s| * sqrt(max(2 - 2*dot, 1e-12)), nontemporal stores
  const float sc = fabsf(scale[0]);
  const int orow0 = tm * BM + wm * 128 + (lane >> 4) * 4;
  const int ocol0 = tn * BN + wn * 64 + fr;
  #pragma unroll
  for (int mi = 0; mi < 8; ++mi) {
    #pragma unroll
    for (int nj = 0; nj < 4; ++nj) {
      const int col = ocol0 + nj * 16;
      #pragma unroll
      for (int r = 0; r < 4; ++r) {
        float d  = acc[mi][nj][r];
        float sq = fmaxf(2.0f - 2.0f * d, 1e-12f);
        __builtin_nontemporal_store(-sc * sqrtf(sq),
            &Out[(size_t)(orow0 + mi * 16 + r) * Cc + col]);
      }
    }
  }
}

extern "C" void kernel_launch(void* const* d_in, const int* in_sizes, int n_in,
                              void* d_out, int out_size, void* d_ws, size_t ws_size,
                              hipStream_t stream) {
  const float* F = (const float*)d_in[0];
  const float* P = (const float*)d_in[1];
  const float* S = (const float*)d_in[2];
  float* Out = (float*)d_out;

  const int D = 1024;
  const int N = in_sizes[0] / D;            // 16384
  const int C = in_sizes[1] / D;            // 8192

  short* Fb = (short*)d_ws;                 // bf16 [N][D]
  short* Pb = Fb + (size_t)N * D;           // bf16 [C][D]

  norm_rows<<<N + C, 256, 0, stream>>>(F, P, Fb, Pb, N);

  dim3 grid((N / BM) * (C / BN));           // 64 * 32 = 2048 tiles
  gemm_epi<<<grid, 512, 0, stream>>>(Fb, Pb, S, Out, N, C, D);
}

// Round 6
// 807.790 us; speedup vs baseline: 1.1480x; 1.0162x over previous
//
#include <hip/hip_runtime.h>
#include <hip/hip_bf16.h>
#include <stdint.h>

using bf16x8 = __attribute__((ext_vector_type(8))) short;
using f32x4  = __attribute__((ext_vector_type(4))) float;

#define SBAR()   __builtin_amdgcn_s_barrier()
#define LGKM0()  asm volatile("s_waitcnt lgkmcnt(0)" ::: "memory")
#define VMW(n)   asm volatile("s_waitcnt vmcnt(" #n ")" ::: "memory")

__device__ __forceinline__ void gload_lds16(const void* g, void* l) {
  __builtin_amdgcn_global_load_lds(
      (const __attribute__((address_space(1))) void*)g,
      (__attribute__((address_space(3))) void*)l,
      16, 0, 0);
}

__device__ __forceinline__ short f2bf(float f) {
  union { float f; uint32_t u; } c; c.f = f;
  uint32_t u = c.u;
  uint32_t r = (u + 0x7fffu + ((u >> 16) & 1u)) >> 16;  // RNE
  return (short)(r & 0xffffu);
}

// ---- L2-normalize rows of 1024 f32 -> bf16. One WAVE per row (no LDS, no
// barriers): 4 rows per 256-thread block.
__global__ __launch_bounds__(256) void norm_rows(
    const float* __restrict__ F, const float* __restrict__ P,
    short* __restrict__ Fb, short* __restrict__ Pb, int nF) {
  const int row  = blockIdx.x * 4 + (threadIdx.x >> 6);
  const int lane = threadIdx.x & 63;
  const float* src; short* dst;
  if (row < nF) {
    src = F + (size_t)row * 1024; dst = Fb + (size_t)row * 1024;
  } else {
    int r = row - nF;
    src = P + (size_t)r * 1024; dst = Pb + (size_t)r * 1024;
  }
  const float4* s4 = (const float4*)src;
  float4 v0 = s4[lane], v1 = s4[lane + 64], v2 = s4[lane + 128], v3 = s4[lane + 192];
  float ss = v0.x*v0.x + v0.y*v0.y + v0.z*v0.z + v0.w*v0.w
           + v1.x*v1.x + v1.y*v1.y + v1.z*v1.z + v1.w*v1.w
           + v2.x*v2.x + v2.y*v2.y + v2.z*v2.z + v2.w*v2.w
           + v3.x*v3.x + v3.y*v3.y + v3.z*v3.z + v3.w*v3.w;
  #pragma unroll
  for (int off = 32; off >= 1; off >>= 1) ss += __shfl_xor(ss, off);
  const float inv = 1.0f / fmaxf(sqrtf(ss), 1e-12f);
  short4* d4 = (short4*)dst;
  short4 o;
  o.x = f2bf(v0.x*inv); o.y = f2bf(v0.y*inv); o.z = f2bf(v0.z*inv); o.w = f2bf(v0.w*inv);
  d4[lane] = o;
  o.x = f2bf(v1.x*inv); o.y = f2bf(v1.y*inv); o.z = f2bf(v1.z*inv); o.w = f2bf(v1.w*inv);
  d4[lane + 64] = o;
  o.x = f2bf(v2.x*inv); o.y = f2bf(v2.y*inv); o.z = f2bf(v2.z*inv); o.w = f2bf(v2.w*inv);
  d4[lane + 128] = o;
  o.x = f2bf(v3.x*inv); o.y = f2bf(v3.y*inv); o.z = f2bf(v3.z*inv); o.w = f2bf(v3.w*inv);
  d4[lane + 192] = o;
}

// ---- 256x256 bf16 NT GEMM, 8-phase counted-vmcnt schedule (T2+T3+T4+T5).
// vs R4: NO sched_barrier(0) pinning (m141), regular stores, hierarchical
// XCD + 4x4-supertile swizzle for L2 reuse. Wait ledger unchanged.
#define BM 256
#define BN 256
#define BK 64

__global__ __launch_bounds__(512, 2) void gemm_epi(
    const short* __restrict__ A,   // [M][K] bf16 bits (normalized features)
    const short* __restrict__ B,   // [Cc][K] bf16 bits (normalized prototypes)
    const float* __restrict__ scale,
    float* __restrict__ Out, int M, int Cc, int K) {
  __shared__ __align__(16) char smem[2 * 65536];   // [buf][A 32K | B 32K]

  const int tid  = threadIdx.x;
  const int wave = tid >> 6;
  const int lane = tid & 63;
  const int wm = wave >> 2;          // 0..1 : M half (128 rows)
  const int wn = wave & 3;           // 0..3 : N quarter (64 cols)
  const int hb = wn >> 1;            // B half for this wave
  const int rbB = (wn & 1) * 4;      // B subtile row-block base within half

  // XCD chunk (8 XCDs x 256 tiles) + 4x4 supertile ordering inside the chunk:
  // 16 consecutive blocks share 4 A-panels + 4 B-panels (4 MB ~= one L2).
  const int x  = blockIdx.x & 7;
  const int c  = blockIdx.x >> 3;          // [0,256)
  const int st = c >> 4, wi = c & 15;
  const int stm = st >> 3, stn = st & 7;
  const int tm = x * 8 + stm * 4 + (wi >> 2);   // [0,64)
  const int tn = stn * 4 + (wi & 3);            // [0,32)

  const size_t Kb = (size_t)K * 2;   // global row stride (bytes)
  const char* Ag = (const char*)A + (size_t)tm * BM * Kb;
  const char* Bg = (const char*)B + (size_t)tn * BN * Kb;

  // Staging inverse map: LDS slot (linear) -> (row,colbyte) of the [128][64]
  // bf16 half-tile in st_16x32 swizzled subtile layout.
  int r0, c0, r1, c1;
  { int s = tid * 16;        int stq = s >> 10, w = s & 1023;
    w ^= ((w >> 9) & 1) << 5; r0 = ((stq >> 1) << 4) + (w >> 6); c0 = ((stq & 1) << 6) + (w & 63); }
  { int s = 8192 + tid * 16; int stq = s >> 10, w = s & 1023;
    w ^= ((w >> 9) & 1) << 5; r1 = ((stq >> 1) << 4) + (w >> 6); c1 = ((stq & 1) << 6) + (w & 63); }

  // Fragment read offset within a 1024B subtile (same swizzle).
  const int fr  = lane & 15;
  const int fk2 = ((lane >> 4) * 8) * 2;                  // {0,16,32,48} bytes
  const int fragoff = fr * 64 + (fk2 ^ ((fr & 8) ? 32 : 0));

  const char* smA = smem + wm * 16384;
  const char* smB = smem + 32768 + hb * 16384;

  f32x4 acc[8][4];
  #pragma unroll
  for (int i = 0; i < 8; ++i)
    #pragma unroll
    for (int j = 0; j < 4; ++j) acc[i][j] = (f32x4){0.f, 0.f, 0.f, 0.f};

  // --- staging half-tiles (2 gload_lds each), read-deadline order ---
  // BLO/BHI: B half-tiles. AEV: subtiles mi0-3 of both A halves (bytes 0-8K).
  // AOD: subtiles mi4-7 (bytes 8-16K). First 6 loads needed at ph0, AOD at ph2.
  #define STG_BLO(t, buf) do { const size_t kb = (size_t)(t) * (BK * 2);       \
    char* db = smem + (buf) * 65536 + wave * 1024;                             \
    gload_lds16(Bg + (size_t)(      r0) * Kb + kb + c0, db + 32768);           \
    gload_lds16(Bg + (size_t)(      r1) * Kb + kb + c1, db + 40960); } while (0)
  #define STG_BHI(t, buf) do { const size_t kb = (size_t)(t) * (BK * 2);       \
    char* db = smem + (buf) * 65536 + wave * 1024;                             \
    gload_lds16(Bg + (size_t)(128 + r0) * Kb + kb + c0, db + 49152);           \
    gload_lds16(Bg + (size_t)(128 + r1) * Kb + kb + c1, db + 57344); } while (0)
  #define STG_AEV(t, buf) do { const size_t kb = (size_t)(t) * (BK * 2);       \
    char* db = smem + (buf) * 65536 + wave * 1024;                             \
    gload_lds16(Ag + (size_t)(      r0) * Kb + kb + c0, db);                   \
    gload_lds16(Ag + (size_t)(128 + r0) * Kb + kb + c0, db + 16384); } while (0)
  #define STG_AOD(t, buf) do { const size_t kb = (size_t)(t) * (BK * 2);       \
    char* db = smem + (buf) * 65536 + wave * 1024;                             \
    gload_lds16(Ag + (size_t)(      r1) * Kb + kb + c1, db + 8192);            \
    gload_lds16(Ag + (size_t)(128 + r1) * Kb + kb + c1, db + 24576); } while (0)

  #define LDA(buf, mi, ks) (*(const bf16x8*)(smA + (buf) * 65536 + ((mi) * 2 + (ks)) * 1024 + fragoff))
  #define LDB(buf, nj, ks) (*(const bf16x8*)(smB + (buf) * 65536 + ((rbB + (nj)) * 2 + (ks)) * 1024 + fragoff))

  #define RD_A(AR, buf, mbase)                                                 \
    _Pragma("unroll")                                                          \
    for (int mi = 0; mi < 4; ++mi) {                                           \
      AR[mi][0] = LDA(buf, (mbase) + mi, 0);                                   \
      AR[mi][1] = LDA(buf, (mbase) + mi, 1); }
  #define RD_B(BR, buf, nbase)                                                 \
    _Pragma("unroll")                                                          \
    for (int nj = 0; nj < 2; ++nj) {                                           \
      BR[nj][0] = LDB(buf, (nbase) + nj, 0);                                   \
      BR[nj][1] = LDB(buf, (nbase) + nj, 1); }
  #define MFMA_Q(mbase, nbase, AR, BR)                                         \
    _Pragma("unroll")                                                          \
    for (int mi = 0; mi < 4; ++mi)                                             \
      _Pragma("unroll")                                                        \
      for (int nj = 0; nj < 2; ++nj) {                                         \
        acc[(mbase)+mi][(nbase)+nj] = __builtin_amdgcn_mfma_f32_16x16x32_bf16( \
            AR[mi][0], BR[nj][0], acc[(mbase)+mi][(nbase)+nj], 0, 0, 0);       \
        acc[(mbase)+mi][(nbase)+nj] = __builtin_amdgcn_mfma_f32_16x16x32_bf16( \
            AR[mi][1], BR[nj][1], acc[(mbase)+mi][(nbase)+nj], 0, 0, 0); }

  const int ni = K / (2 * BK);   // iterations; 2 K-tiles each

  // Prologue: stage tile 0 -> buf0; wait first 6 (B all + A mi0-3).
  STG_BLO(0, 0); STG_BHI(0, 0); STG_AEV(0, 0); STG_AOD(0, 0);
  VMW(2); SBAR();

  for (int i = 0; i < ni; ++i) {
    const int t1 = 2 * i + 1;          // staged ph0-3 -> buf1, read ph4-7
    const int t2 = 2 * i + 2;          // staged ph4-7 -> buf0, read next iter
    const bool last = (i == ni - 1);

    bf16x8 a03[4][2], a47[4][2], bA[2][2], bB[2][2];

    // ph0: tile 2i quadrant (mi0-3, nj0-1)
    RD_A(a03, 0, 0); RD_B(bA, 0, 0);
    STG_BLO(t1, 1);
    SBAR(); LGKM0();
    __builtin_amdgcn_s_setprio(1); MFMA_Q(0, 0, a03, bA) __builtin_amdgcn_s_setprio(0);
    SBAR();

    // ph1: (mi0-3, nj2-3)  [A reused]
    RD_B(bB, 0, 2);
    STG_BHI(t1, 1);
    SBAR(); LGKM0();
    __builtin_amdgcn_s_setprio(1); MFMA_Q(0, 2, a03, bB) __builtin_amdgcn_s_setprio(0);
    VMW(4);                            // tile 2i AOD landed (needed ph2)
    SBAR();

    // ph2: (mi4-7, nj2-3)  [B reused]
    RD_A(a47, 0, 4);
    STG_AEV(t1, 1);
    SBAR(); LGKM0();
    __builtin_amdgcn_s_setprio(1); MFMA_Q(4, 2, a47, bB) __builtin_amdgcn_s_setprio(0);
    SBAR();

    // ph3: (mi4-7, nj0-1)  [B re-read]
    RD_B(bA, 0, 0);
    STG_AOD(t1, 1);
    SBAR(); LGKM0();
    __builtin_amdgcn_s_setprio(1); MFMA_Q(4, 0, a47, bA) __builtin_amdgcn_s_setprio(0);
    VMW(2);                            // tile t1 first-6 landed (needed ph4)
    SBAR();

    // ph4: tile t1 quadrant (mi0-3, nj0-1)
    RD_A(a03, 1, 0); RD_B(bA, 1, 0);
    if (!last) { STG_BLO(t2, 0); }
    SBAR(); LGKM0();
    __builtin_amdgcn_s_setprio(1); MFMA_Q(0, 0, a03, bA) __builtin_amdgcn_s_setprio(0);
    SBAR();

    // ph5: (mi0-3, nj2-3)
    RD_B(bB, 1, 2);
    if (!last) { STG_BHI(t2, 0); }
    SBAR(); LGKM0();
    __builtin_amdgcn_s_setprio(1); MFMA_Q(0, 2, a03, bB) __builtin_amdgcn_s_setprio(0);
    if (!last) { VMW(4); } else { VMW(0); }   // tile t1 AOD landed (needed ph6)
    SBAR();

    // ph6: (mi4-7, nj2-3)
    RD_A(a47, 1, 4);
    if (!last) { STG_AEV(t2, 0); }
    SBAR(); LGKM0();
    __builtin_amdgcn_s_setprio(1); MFMA_Q(4, 2, a47, bB) __builtin_amdgcn_s_setprio(0);
    SBAR();

    // ph7: (mi4-7, nj0-1)
    RD_B(bA, 1, 0);
    if (!last) { STG_AOD(t2, 0); }
    SBAR(); LGKM0();
    __builtin_amdgcn_s_setprio(1); MFMA_Q(4, 0, a47, bA) __builtin_amdgcn_s_setprio(0);
    VMW(2);                            // tile t2 first-6 landed (next ph0)
    SBAR();
  }

  // epilogue: out = -|s| * sqrt(max(2 - 2*dot, 1e-12))
  const float sc = fabsf(scale[0]);
  const int orow0 = tm * BM + wm * 128 + (lane >> 4) * 4;
  const int ocol0 = tn * BN + wn * 64 + fr;
  #pragma unroll
  for (int mi = 0; mi < 8; ++mi) {
    #pragma unroll
    for (int nj = 0; nj < 4; ++nj) {
      const int col = ocol0 + nj * 16;
      #pragma unroll
      for (int r = 0; r < 4; ++r) {
        float d  = acc[mi][nj][r];
        float sq = fmaxf(2.0f - 2.0f * d, 1e-12f);
        Out[(size_t)(orow0 + mi * 16 + r) * Cc + col] = -sc * sqrtf(sq);
      }
    }
  }
}

extern "C" void kernel_launch(void* const* d_in, const int* in_sizes, int n_in,
                              void* d_out, int out_size, void* d_ws, size_t ws_size,
                              hipStream_t stream) {
  const float* F = (const float*)d_in[0];
  const float* P = (const float*)d_in[1];
  const float* S = (const float*)d_in[2];
  float* Out = (float*)d_out;

  const int D = 1024;
  const int N = in_sizes[0] / D;            // 16384
  const int C = in_sizes[1] / D;            // 8192

  short* Fb = (short*)d_ws;                 // bf16 [N][D]
  short* Pb = Fb + (size_t)N * D;           // bf16 [C][D]

  norm_rows<<<(N + C) / 4, 256, 0, stream>>>(F, P, Fb, Pb, N);

  dim3 grid((N / BM) * (C / BN));           // 64 * 32 = 2048 tiles
  gemm_epi<<<grid, 512, 0, stream>>>(Fb, Pb, S, Out, N, C, D);
}